// Round 3
// baseline (147.839 us; speedup 1.0000x reference)
//
#include <hip/hip_runtime.h>

#define NF 26
#define ND 32
#define NPAIR 325                 // NF*(NF-1)/2
#define ROW_F4 (NF * ND / 4)      // 208 float4 per input batch-row
#define OUT_F4 (NPAIR * ND / 4)   // 2600 float4 per output batch-row
#define ROWS 4                    // batch rows per group
#define GROUPS_PER_BLOCK 4        // 16 rows per block
#define GROUP_F4 (ROWS * ROW_F4)  // 832 float4 per group
#define NTHREADS 256
#define KFULL (OUT_F4 / NTHREADS) // 10 full sweeps per row
#define KTAIL (OUT_F4 % NTHREADS) // 40-thread tail

typedef float f32x4 __attribute__((ext_vector_type(4)));

// Compile-time pair table: entry p packs (i*8) | (j*8)<<8 in float4 units.
struct PairTab { unsigned short v[NPAIR]; };
constexpr PairTab make_tab() {
    PairTab t{};
    int n = 0;
    for (int i = 0; i < NF; ++i)
        for (int j = i + 1; j < NF; ++j)
            t.v[n++] = (unsigned short)((i * (ND / 4)) | ((j * (ND / 4)) << 8));
    return t;
}
__constant__ PairTab c_tab = make_tab();

__global__ __launch_bounds__(NTHREADS) void interaction_kernel(
    const f32x4* __restrict__ in, f32x4* __restrict__ out)
{
    __shared__ f32x4 s[2][GROUP_F4];   // 2 x 13 KB double buffer

    const int tid = threadIdx.x;
    const long g0 = (long)blockIdx.x * GROUPS_PER_BLOCK;

    // Per-thread LDS element offsets (row-relative), hoisted to registers.
    int aoff[KFULL + 1], boff[KFULL + 1];
    #pragma unroll
    for (int k = 0; k <= KFULL; ++k) {
        const int q = (k < KFULL) ? (tid + k * NTHREADS)
                                  : (KFULL * NTHREADS + (tid < KTAIL ? tid : 0));
        const unsigned int t = c_tab.v[q >> 3];   // pair index = q/8
        const int d = q & 7;
        aoff[k] = (int)(t & 0xffu) + d;
        boff[k] = (int)(t >> 8) + d;
    }

    // Prologue: stage group g0 into s[0] (coalesced).
    {
        const f32x4* __restrict__ src = in + g0 * GROUP_F4;
        #pragma unroll
        for (int k = 0; k < 3; ++k) s[0][tid + k * NTHREADS] = src[tid + k * NTHREADS];
        if (tid < GROUP_F4 - 3 * NTHREADS) s[0][tid + 3 * NTHREADS] = src[tid + 3 * NTHREADS];
    }
    __syncthreads();

    #pragma unroll 1
    for (int g = 0; g < GROUPS_PER_BLOCK; ++g) {
        const int p = g & 1;
        const bool has_next = (g + 1 < GROUPS_PER_BLOCK);

        // Issue next group's global loads into registers NOW; the ~6 us of
        // stores below hides the HBM latency (compiler inserts the waits
        // before the ds_write at the bottom).
        f32x4 pf0, pf1, pf2, pf3;
        if (has_next) {
            const f32x4* __restrict__ src = in + (g0 + g + 1) * GROUP_F4;
            pf0 = src[tid];
            pf1 = src[tid + NTHREADS];
            pf2 = src[tid + 2 * NTHREADS];
            if (tid < GROUP_F4 - 3 * NTHREADS) pf3 = src[tid + 3 * NTHREADS];
        }

        // Compute + store group g from s[p]. Fully coalesced nontemporal
        // float4 stores, LDS reads conflict-light.
        const long baseRow = (g0 + g) * ROWS;
        #pragma unroll 1
        for (int r = 0; r < ROWS; ++r) {
            const f32x4* __restrict__ row = &s[p][r * ROW_F4];
            f32x4* __restrict__ dst = out + (baseRow + r) * OUT_F4;
            #pragma unroll
            for (int k = 0; k < KFULL; ++k) {
                const f32x4 rr = row[aoff[k]] * row[boff[k]];
                __builtin_nontemporal_store(rr, dst + tid + k * NTHREADS);
            }
            if (tid < KTAIL) {
                const f32x4 rr = row[aoff[KFULL]] * row[boff[KFULL]];
                __builtin_nontemporal_store(rr, dst + KFULL * NTHREADS + tid);
            }
        }

        if (has_next) {
            __syncthreads();   // all waves done reading s[1-p] (group g-1)
            s[1 - p][tid] = pf0;
            s[1 - p][tid + NTHREADS] = pf1;
            s[1 - p][tid + 2 * NTHREADS] = pf2;
            if (tid < GROUP_F4 - 3 * NTHREADS) s[1 - p][tid + 3 * NTHREADS] = pf3;
            __syncthreads();   // s[1-p] ready for group g+1
        }
    }
}

extern "C" void kernel_launch(void* const* d_in, const int* in_sizes, int n_in,
                              void* d_out, int out_size, void* d_ws, size_t ws_size,
                              hipStream_t stream) {
    const f32x4* in  = (const f32x4*)d_in[0];
    f32x4*       out = (f32x4*)d_out;
    const int B = in_sizes[0] / (NF * ND);                 // 16384
    const int blocks = B / (ROWS * GROUPS_PER_BLOCK);      // 1024
    interaction_kernel<<<blocks, NTHREADS, 0, stream>>>(in, out);
}

// Round 4
// 138.628 us; speedup vs baseline: 1.0664x; 1.0664x over previous
//
#include <hip/hip_runtime.h>

#define NF 26
#define ND 32
#define NPAIR 325                 // NF*(NF-1)/2
#define ROW_F4 (NF * ND / 4)      // 208 float4 per input batch-row
#define OUT_F4 (NPAIR * ND / 4)   // 2600 float4 per output batch-row
#define ROWS_PER_WAVE 8
#define NTHREADS 256
#define ROWS_PER_BLOCK (ROWS_PER_WAVE * NTHREADS / 64)   // 32

typedef float f32x4 __attribute__((ext_vector_type(4)));

// Register-resident interaction: each lane owns one (row, d4) column slice.
// lane = r*8 + d4 : holds in[row, f, 4*d4 .. 4*d4+3] for all 26 f in VGPRs.
// Pair loop is wave-uniform with compile-time register indices -> no LDS,
// no barriers, no divergence, ~5 instructions per 1KB wave-store.
__global__ __launch_bounds__(NTHREADS) void interaction_kernel(
    const f32x4* __restrict__ in, f32x4* __restrict__ out)
{
    const int tid  = threadIdx.x;
    const int wave = tid >> 6;
    const int lane = tid & 63;
    const int r    = lane >> 3;   // 0..7: row within this wave's 8 rows
    const int d4   = lane & 7;    // 0..7: float4 column within D=32

    const long row = (long)blockIdx.x * ROWS_PER_BLOCK + wave * ROWS_PER_WAVE + r;

    // Load this lane's column: 26 float4 at 128B stride, all from one base
    // with immediate offsets (f*128 <= 3200 < 4096).
    const f32x4* __restrict__ src = in + row * ROW_F4 + d4;
    f32x4 a[NF];
    #pragma unroll
    for (int f = 0; f < NF; ++f) a[f] = src[f * (ND / 4)];

    // 325 wave-uniform pair products; store offsets compile-time (p*128B).
    f32x4* __restrict__ dst = out + row * OUT_F4 + d4;
    int p = 0;
    #pragma unroll
    for (int i = 0; i < NF; ++i) {
        #pragma unroll
        for (int j = i + 1; j < NF; ++j) {
            __builtin_nontemporal_store(a[i] * a[j], dst + p * (ND / 4));
            ++p;
        }
    }
}

extern "C" void kernel_launch(void* const* d_in, const int* in_sizes, int n_in,
                              void* d_out, int out_size, void* d_ws, size_t ws_size,
                              hipStream_t stream) {
    const f32x4* in  = (const f32x4*)d_in[0];
    f32x4*       out = (f32x4*)d_out;
    const int B = in_sizes[0] / (NF * ND);          // 16384
    const int blocks = B / ROWS_PER_BLOCK;          // 512
    interaction_kernel<<<blocks, NTHREADS, 0, stream>>>(in, out);
}